// Round 2
// baseline (351.899 us; speedup 1.0000x reference)
//
#include <hip/hip_runtime.h>
#include <math.h>

#define NCAP 10
#define IC 6912
#define ID 16
#define OD 16
#define STOT (64 * NCAP * OD)   // 10240 floats per s image

typedef __attribute__((ext_vector_type(4))) float f32x4;
typedef __attribute__((ext_vector_type(8))) short bf16x8;

// fp32 -> bf16 RNE
static __device__ inline unsigned short f2bf(float f) {
    unsigned int u = __float_as_uint(f);
    unsigned int r = u + 0x7FFFu + ((u >> 16) & 1u);
    return (unsigned short)(r >> 16);
}

// MFMA routing sweep.
// Block: 256 threads = 4 waves; wave w owns b-group w*16..w*16+15.
// Per j: u_hat tile via mfma_f32_16x16x32_bf16 with M=o (A=W^T), N=b (B=x),
// K=i zero-padded 16->32 (rows store 16 data + 16 zeros + 8 pad).
// D layout (m89): col=lane&15 (=b), row=(lane>>4)*4+reg (=o).
__global__ __launch_bounds__(256, 3) void sweep_kernel(
    const float* __restrict__ x, const float* __restrict__ W,
    const float* __restrict__ vsum, float* __restrict__ s_part,
    int iter, int jcount)
{
    // row stride 40 bf16 (80 B): 16-byte aligned rows, ~2-way banks max
    __shared__ unsigned short w_t[NCAP * 16 * 40];  // [n][o][i(16)+zeros(16)+pad(8)]
    __shared__ unsigned short x_t[64 * 40];         // [b][i(16)+zeros(16)+pad(8)]

    const int tid  = threadIdx.x;
    const int lane = tid & 63;
    const int wave = tid >> 6;
    const int bl   = lane & 15;       // MFMA col index (= local b)
    const int kq   = lane >> 4;       // k-slice quad / D row quad
    const int b    = wave * 16 + bl;  // global batch index
    const int j0   = blockIdx.x * jcount;

    // zero-init LDS once (keeps the k=16..31 zero pad valid across all j)
    for (int idx = tid; idx < (NCAP * 16 * 40) / 2; idx += 256)
        ((unsigned int*)w_t)[idx] = 0u;
    for (int idx = tid; idx < (64 * 40) / 2; idx += 256)
        ((unsigned int*)x_t)[idx] = 0u;

    // vsum fragment in registers: vv[n] = vsum[b, n, kq*4 .. +3]
    f32x4 vv[NCAP];
    if (iter > 0) {
        #pragma unroll
        for (int n = 0; n < NCAP; ++n)
            vv[n] = *(const f32x4*)&vsum[(b * NCAP + n) * OD + kq * 4];
    }

    f32x4 sac[NCAP];
    #pragma unroll
    for (int n = 0; n < NCAP; ++n) sac[n] = (f32x4){0.f, 0.f, 0.f, 0.f};

    const float4* __restrict__ W4 = (const float4*)W;
    const float4* __restrict__ X4 = (const float4*)x;

    for (int jj = 0; jj < jcount; ++jj) {
        const int j = j0 + jj;
        __syncthreads();  // protect previous iteration's LDS reads

        // stage W[:, j, :, :] transposed -> w_t[n][o][i] as bf16
        for (int f = tid; f < 640; f += 256) {
            const int n  = f >> 6;
            const int r  = f & 63;          // i*4 + oq
            const int i  = r >> 2;
            const int oq = r & 3;
            float4 w = W4[(size_t)n * IC * 64 + (size_t)j * 64 + r];
            const int base = (n * 16 + oq * 4) * 40 + i;
            w_t[base + 0 * 40] = f2bf(w.x);
            w_t[base + 1 * 40] = f2bf(w.y);
            w_t[base + 2 * 40] = f2bf(w.z);
            w_t[base + 3 * 40] = f2bf(w.w);
        }
        // stage x[:, j, :] -> x_t[b][i] as bf16 (uint2 = 4 bf16 write)
        {
            const int bb = tid >> 2;
            const int iq = tid & 3;
            float4 xv = X4[(size_t)bb * IC * 4 + (size_t)j * 4 + iq];
            unsigned int lo = (unsigned int)f2bf(xv.x) | ((unsigned int)f2bf(xv.y) << 16);
            unsigned int hi = (unsigned int)f2bf(xv.z) | ((unsigned int)f2bf(xv.w) << 16);
            *(uint2*)&x_t[bb * 40 + iq * 4] = make_uint2(lo, hi);
        }
        __syncthreads();

        // B operand: x fragment (shared across all n)
        bf16x8 xb = *(const bf16x8*)&x_t[(wave * 16 + bl) * 40 + kq * 8];

        // u[n] = W[n]^T (M=o,K=i) x x (K=i,N=b)
        f32x4 u[NCAP];
        const f32x4 zero = (f32x4){0.f, 0.f, 0.f, 0.f};
        #pragma unroll
        for (int n = 0; n < NCAP; ++n) {
            bf16x8 af = *(const bf16x8*)&w_t[(n * 16 + bl) * 40 + kq * 8];
            u[n] = __builtin_amdgcn_mfma_f32_16x16x32_bf16(af, xb, zero, 0, 0, 0);
        }

        if (iter == 0) {
            #pragma unroll
            for (int n = 0; n < NCAP; ++n) {
                sac[n].x = fmaf(0.1f, u[n].x, sac[n].x);
                sac[n].y = fmaf(0.1f, u[n].y, sac[n].y);
                sac[n].z = fmaf(0.1f, u[n].z, sac[n].z);
                sac[n].w = fmaf(0.1f, u[n].w, sac[n].w);
            }
        } else {
            // bb[n] = sum_o u * vsum : 4 in-lane + butterfly over lane bits 4,5
            float bb_[NCAP];
            #pragma unroll
            for (int n = 0; n < NCAP; ++n) {
                float p = u[n].x * vv[n].x + u[n].y * vv[n].y
                        + u[n].z * vv[n].z + u[n].w * vv[n].w;
                p += __shfl_xor(p, 16);
                p += __shfl_xor(p, 32);
                bb_[n] = p;
            }
            float m = bb_[0];
            #pragma unroll
            for (int n = 1; n < NCAP; ++n) m = fmaxf(m, bb_[n]);
            float ssum = 0.f;
            float c[NCAP];
            #pragma unroll
            for (int n = 0; n < NCAP; ++n) { c[n] = __expf(bb_[n] - m); ssum += c[n]; }
            const float inv = 1.0f / ssum;
            #pragma unroll
            for (int n = 0; n < NCAP; ++n) {
                const float cn = c[n] * inv;
                sac[n].x = fmaf(cn, u[n].x, sac[n].x);
                sac[n].y = fmaf(cn, u[n].y, sac[n].y);
                sac[n].z = fmaf(cn, u[n].z, sac[n].z);
                sac[n].w = fmaf(cn, u[n].w, sac[n].w);
            }
        }
    }

    // write block partial: s_part[blk][b, n, o]; lanes {b, b+16, b+32, b+48}
    // cover each 64B line fully -> coalesced
    float* sp = s_part + (size_t)blockIdx.x * STOT;
    #pragma unroll
    for (int n = 0; n < NCAP; ++n)
        *(f32x4*)&sp[(b * NCAP + n) * OD + kq * 4] = sac[n];
}

// stage 1: sum nslots partials down to 8
__global__ __launch_bounds__(256) void reduce1_kernel(
    const float* __restrict__ s_part, float* __restrict__ stage2, int kper)
{
    const int g4 = blockIdx.x * 256 + threadIdx.x;   // float4 index 0..2559
    const int k0 = blockIdx.y * kper;
    const float4* sp4 = (const float4*)s_part;
    float4 acc = make_float4(0.f, 0.f, 0.f, 0.f);
    for (int k = 0; k < kper; ++k) {
        float4 v = sp4[(size_t)(k0 + k) * (STOT / 4) + g4];
        acc.x += v.x; acc.y += v.y; acc.z += v.z; acc.w += v.w;
    }
    ((float4*)stage2)[(size_t)blockIdx.y * (STOT / 4) + g4] = acc;
}

// stage 2: sum 8, squash, maintain vsum / write out
__global__ __launch_bounds__(256) void reduce2_kernel(
    const float* __restrict__ stage2, float* __restrict__ vsum,
    float* __restrict__ out, int iter)
{
    const int g = blockIdx.x * 256 + threadIdx.x;   // 0..10239
    float acc = 0.f;
    #pragma unroll
    for (int kb = 0; kb < 8; ++kb) acc += stage2[kb * STOT + g];

    float sq = acc * acc;
    sq += __shfl_xor(sq, 1);
    sq += __shfl_xor(sq, 2);
    sq += __shfl_xor(sq, 4);
    sq += __shfl_xor(sq, 8);
    float scale = (sq / (1.f + sq)) / sqrtf(sq + 1e-7f);
    float v = scale * acc;

    if (iter == 2)      out[g] = v;
    else if (iter == 0) vsum[g] = v;
    else                vsum[g] += v;
}

extern "C" void kernel_launch(void* const* d_in, const int* in_sizes, int n_in,
                              void* d_out, int out_size, void* d_ws, size_t ws_size,
                              hipStream_t stream) {
    (void)in_sizes; (void)n_in; (void)out_size;
    const float* x = (const float*)d_in[0];   // [64, 6912, 16]
    const float* W = (const float*)d_in[1];   // [10, 6912, 16, 16]
    float* out = (float*)d_out;               // [64, 10, 16]

    // prefer 864 blocks (JB=8) for occupancy; fall back to 432 if ws is small
    const size_t need_big = ((size_t)864 * STOT + 8 * STOT + STOT) * 4;
    int nslots, jcount;
    if (ws_size >= need_big) { nslots = 864; jcount = 8; }
    else                     { nslots = 432; jcount = 16; }

    float* s_part = (float*)d_ws;
    float* stage2 = s_part + (size_t)nslots * STOT;
    float* vsum   = stage2 + (size_t)8 * STOT;

    for (int iter = 0; iter < 3; ++iter) {
        sweep_kernel<<<nslots, 256, 0, stream>>>(x, W, vsum, s_part, iter, jcount);
        reduce1_kernel<<<dim3(10, 8), 256, 0, stream>>>(s_part, stage2, nslots / 8);
        reduce2_kernel<<<40, 256, 0, stream>>>(stage2, vsum, out, iter);
    }
}